// Round 8
// baseline (169.664 us; speedup 1.0000x reference)
//
#include <hip/hip_runtime.h>

// DCNv2 B=4,C=256,H=W=64,OC=256,K=9. Pipeline:
//   wprep_A   : weight -> WtA[o][ck] bf16 (ck=k*256+c)
//   owb_prep  : offset_w -> owb[k][32ch pad][256c] bf16
//   om_init   : om = obias broadcast
//   xprep2    : x NCHW f32 -> xT[b][p][c] bf16 (NHWC), LDS-transposed coalesced
//   offs_mfma2: offset conv as 9-shift MFMA GEMM, c-split x2, atomic reduce -> om
//   dcn_main  : FUSED gather+GEMM: per (b, p-row) block, gather B-tile into LDS
//               from xt (no sbuf round-trip), A from wta via global_load_lds,
//               bf16 MFMA 16x16x32, 256o x 64p, 8 waves, double-buffered.

#define NB 4
#define NC 256
#define HW 64
#define NP 4096
#define NOC 256
#define NCK 2304
#define ROWB 4608           // bytes per ck-row (2304 * 2B)
#define NKT2 36             // 64-ck tiles

typedef __attribute__((ext_vector_type(8))) short short8;
typedef __attribute__((ext_vector_type(4))) float f32x4;
typedef unsigned short ushort_t;
typedef unsigned int uint32;

__device__ __forceinline__ void gload16(const void* g, void* l) {
    __builtin_amdgcn_global_load_lds(
        (const __attribute__((address_space(1))) unsigned int*)g,
        (__attribute__((address_space(3))) unsigned int*)l, 16, 0, 0);
}

__device__ __forceinline__ uint32 f2bf(float v) {
    uint32 b = __float_as_uint(v);
    return (b + 0x7FFFu + ((b >> 16) & 1u)) >> 16;   // RNE
}
__device__ __forceinline__ float bf_lo(uint32 u) { return __uint_as_float(u << 16); }
__device__ __forceinline__ float bf_hi(uint32 u) { return __uint_as_float(u & 0xFFFF0000u); }

// ---------------------------------------------------------------- wprep_A
__global__ __launch_bounds__(256) void wprep_A(const float* __restrict__ w,
                                               ushort_t* __restrict__ wta) {
    int e = blockIdx.x * 256 + threadIdx.x;     // < 256*2304
    int o  = e / NCK;
    int ck = e - o * NCK;
    int c = ck & 255;
    int k = ck >> 8;
    wta[e] = (ushort_t)f2bf(w[o * NCK + c * 9 + k]);
}

// ---------------------------------------------------------------- owb_prep
__global__ __launch_bounds__(256) void owb_prep(const float* __restrict__ ow,
                                                ushort_t* __restrict__ owb) {
    int e = blockIdx.x * 256 + threadIdx.x;     // < 73728
    int c = e & 255;
    int r = e >> 8;          // k*32 + ch
    int ch = r & 31;
    int k = r >> 5;
    float v = 0.f;
    if (ch < 27) v = ow[(ch * NC + c) * 9 + k];
    owb[e] = (ushort_t)f2bf(v);
}

// ---------------------------------------------------------------- om_init
__global__ __launch_bounds__(256) void om_init(const float* __restrict__ obias,
                                               float* __restrict__ om) {
    int g = blockIdx.x * 256 + threadIdx.x;     // < 4*27*4096
    int r = g >> 12;
    int ch = r % 27;
    om[g] = obias[ch];
}

// ---------------------------------------------------------------- xprep2
__global__ __launch_bounds__(256) void xprep2(const float* __restrict__ x,
                                              ushort_t* __restrict__ xt) {
    __shared__ float tr[128 * 65];    // 33280 B
    int bid = blockIdx.x;             // b*128 + cc*32 + pt
    int pt = bid & 31;
    int cc = (bid >> 5) & 3;
    int b  = bid >> 7;
    int t = threadIdx.x;
    int c0 = cc * 64;

    const float* xb = x + ((size_t)(b * NC + c0)) * NP + pt * 128;
    #pragma unroll
    for (int pass = 0; pass < 8; ++pass) {
        int c  = pass * 8 + (t >> 5);
        int p4 = (t & 31) * 4;
        float4 v = *(const float4*)(xb + (size_t)c * NP + p4);
        tr[(p4 + 0) * 65 + c] = v.x;
        tr[(p4 + 1) * 65 + c] = v.y;
        tr[(p4 + 2) * 65 + c] = v.z;
        tr[(p4 + 3) * 65 + c] = v.w;
    }
    __syncthreads();
    ushort_t* xto = xt + ((size_t)b * NP + pt * 128) * NC + c0;
    #pragma unroll
    for (int pass = 0; pass < 4; ++pass) {
        int e = pass * 256 + t;
        int p = e >> 3, seg = e & 7;
        const float* rp = &tr[p * 65 + seg * 8];
        uint32 pk[4];
        #pragma unroll
        for (int h = 0; h < 4; ++h)
            pk[h] = f2bf(rp[2 * h]) | (f2bf(rp[2 * h + 1]) << 16);
        *(uint4*)(xto + (size_t)p * NC + seg * 8) = make_uint4(pk[0], pk[1], pk[2], pk[3]);
    }
}

// ---------------------------------------------------------------- offs_mfma2
__global__ __launch_bounds__(256) void offs_mfma2(const ushort_t* __restrict__ xt,
                                                  const ushort_t* __restrict__ owb,
                                                  float* __restrict__ om) {
    __shared__ __align__(16) char lds[65376];
    int bid = blockIdx.x;        // b*128 + y*2 + h
    int h = bid & 1;
    int y = (bid >> 1) & 63;
    int b = bid >> 7;
    int t = threadIdx.x;
    int lane = t & 63;
    int w = t >> 6;
    int r16 = lane & 15;
    int g   = lane >> 4;

    f32x4 acc[2][4];
    #pragma unroll
    for (int mf = 0; mf < 2; ++mf)
        #pragma unroll
        for (int nf = 0; nf < 4; ++nf) acc[mf][nf] = (f32x4){0.f, 0.f, 0.f, 0.f};

    const ushort_t* xtb = xt + ((size_t)b * NP) * NC;

    for (int ccc = 0; ccc < 2; ++ccc) {
        int c0 = (h * 2 + ccc) * 64;
        __syncthreads();
        for (int e = t; e < 1584; e += 256) {
            int rr = e >> 3, seg = e & 7;
            int dy = (rr >= 132) ? 2 : (rr >= 66 ? 1 : 0);
            int xx = rr - dy * 66;
            int ys = y + dy - 1;
            int xs = xx - 1;
            uint4 v = make_uint4(0, 0, 0, 0);
            if (ys >= 0 && ys < 64 && xs >= 0 && xs < 64)
                v = *(const uint4*)(xtb + ((ys << 6) + xs) * NC + c0 + seg * 8);
            *(uint4*)(lds + rr * 144 + seg * 16) = v;
        }
        for (int e = t; e < 2304; e += 256) {
            int row = e >> 3;        // k*32 + ch
            int seg = e & 7;
            uint4 v = *(const uint4*)(owb + (row << 8) + c0 + seg * 8);
            *(uint4*)(lds + 28512 + (row << 7) + seg * 16) = v;
        }
        __syncthreads();
        for (int s = w; s < 9; s += 4) {
            int dy = (s >= 6) ? 2 : (s >= 3 ? 1 : 0);
            int dx = s - dy * 3;
            const char* Ab = lds + 28512 + s * 4096;
            #pragma unroll
            for (int ks = 0; ks < 2; ++ks) {
                short8 a0 = *(const short8*)(Ab + r16 * 128 + ks * 64 + g * 16);
                short8 a1 = *(const short8*)(Ab + (16 + r16) * 128 + ks * 64 + g * 16);
                #pragma unroll
                for (int nf = 0; nf < 4; ++nf) {
                    short8 bv = *(const short8*)(lds +
                        (dy * 66 + nf * 16 + r16 + dx) * 144 + ks * 64 + g * 16);
                    acc[0][nf] = __builtin_amdgcn_mfma_f32_16x16x32_bf16(
                        a0, bv, acc[0][nf], 0, 0, 0);
                    acc[1][nf] = __builtin_amdgcn_mfma_f32_16x16x32_bf16(
                        a1, bv, acc[1][nf], 0, 0, 0);
                }
            }
        }
    }
    __syncthreads();
    float* red = (float*)lds;
    #pragma unroll
    for (int mf = 0; mf < 2; ++mf)
        #pragma unroll
        for (int nf = 0; nf < 4; ++nf)
            #pragma unroll
            for (int r = 0; r < 4; ++r) {
                int ch = mf * 16 + g * 4 + r;
                int p  = nf * 16 + r16;
                red[((w * 32 + ch) << 6) + p] = acc[mf][nf][r];
            }
    __syncthreads();
    for (int e = t; e < 27 * 64; e += 256) {
        int ch = e >> 6, p = e & 63;
        float sres = red[(ch << 6) + p] + red[((32 + ch) << 6) + p]
                   + red[((64 + ch) << 6) + p] + red[((96 + ch) << 6) + p];
        atomicAdd(&om[((size_t)(b * 27 + ch)) * NP + (y << 6) + p], sres);
    }
}

// ---------------------------------------------------------------- dcn_main
// Fused gather+GEMM. Block=(b, pt): 256o x 64p (row y=pt). 512 thr / 8 waves.
// LDS: A dbuf 2x[256 o][144B] = 73728 | B dbuf 2x[64 p][144B] = 18432 |
//      ci int4[576] = 9216 | cw float4[576] = 9216  => 110592 B (1 block/CU).
// Per 64-ck tile: stage A (global_load_lds, /9 src remap for 144B pad rows);
// gather B: 4 scattered uint4 corner loads + FMA + bf16 pack + ds_write_b128.
// Wave (wo=w&3, wp=w>>2): 64o x 32p = 4x2 frags, 16 MFMA / tile.
__global__ __launch_bounds__(512, 1) void dcn_main(const ushort_t* __restrict__ wta,
                                                   const ushort_t* __restrict__ xt,
                                                   const float* __restrict__ om,
                                                   const float* __restrict__ bias,
                                                   float* __restrict__ out) {
    __shared__ __align__(16) char lds[110592];
    char*   ldsA = lds;                       // 2 x 36864
    char*   ldsB = lds + 73728;               // 2 x 9216
    int4*   ci_l = (int4*)(lds + 92160);      // [9][64]
    float4* cw_l = (float4*)(lds + 101376);   // [9][64]

    int bid = blockIdx.x;                     // 256 blocks
    int b  = (bid & 7) >> 1;                  // XCD pair per batch
    int pt = ((bid >> 3) << 1) | (bid & 1);   // 0..63 (= output row y)
    int t  = threadIdx.x;
    int lane = t & 63;
    int w  = t >> 6;
    int wo = w & 3;
    int wp = w >> 2;
    int r16 = lane & 15;
    int g   = lane >> 4;

    // ---- coords for all (k, pl) of this row
    for (int e = t; e < 576; e += 512) {
        int k  = e >> 6;
        int pl = e & 63;
        int p  = (pt << 6) + pl;
        const float* omb = om + ((size_t)b * 27) * NP;
        float o1 = omb[(size_t)k * NP + p];
        float o2 = omb[(size_t)(9 + k) * NP + p];
        float ml = omb[(size_t)(18 + k) * NP + p];
        float mask = 1.f / (1.f + expf(-ml));
        float sx = (float)pl + (float)(k % 3) - 2.0f + o1;
        float sy = (float)pt + (float)(k / 3) - 2.0f + o2;
        float x0f = floorf(sx), y0f = floorf(sy);
        float fx = sx - x0f, fy = sy - y0f;
        int idv[4]; float wgt[4];
        #pragma unroll
        for (int cy = 0; cy < 2; ++cy) {
            float yf = y0f + (float)cy;
            float wy = cy ? fy : 1.f - fy;
            #pragma unroll
            for (int cx = 0; cx < 2; ++cx) {
                float xf = x0f + (float)cx;
                float wx = cx ? fx : 1.f - fx;
                bool valid = (xf >= 0.f) && (xf <= 63.f) && (yf >= 0.f) && (yf <= 63.f);
                int xi = min(max((int)xf, 0), 63);
                int yi = min(max((int)yf, 0), 63);
                idv[cy * 2 + cx] = yi * HW + xi;
                wgt[cy * 2 + cx] = valid ? wx * wy * mask : 0.f;
            }
        }
        ci_l[e] = make_int4(idv[0], idv[1], idv[2], idv[3]);
        cw_l[e] = make_float4(wgt[0], wgt[1], wgt[2], wgt[3]);
    }
    __syncthreads();

    const ushort_t* xtb = xt + ((size_t)b * NP) * NC;
    int pl = lane;                            // gather role: p-lane, c-group = w

    f32x4 acc[4][2];
    #pragma unroll
    for (int fo = 0; fo < 4; ++fo)
        #pragma unroll
        for (int fp = 0; fp < 2; ++fp) acc[fo][fp] = (f32x4){0.f, 0.f, 0.f, 0.f};

    // ---- prologue: stage tile 0 into half 0
    {
        #pragma unroll
        for (int j = 0; j < 5; ++j) {
            int chunk = j * 512 + t;
            if (chunk < 2304) {
                int row  = chunk / 9;
                int slot = chunk - row * 9; if (slot > 7) slot = 7;
                gload16((const char*)wta + (size_t)row * ROWB + slot * 16,
                        ldsA + chunk * 16);
            }
        }
        int4   id = ci_l[pl];                 // k=0, c0=0
        float4 cwv = cw_l[pl];
        const ushort_t* xb = xtb + w * 8;
        uint4 q0 = *(const uint4*)(xb + (size_t)id.x * NC);
        uint4 q1 = *(const uint4*)(xb + (size_t)id.y * NC);
        uint4 q2 = *(const uint4*)(xb + (size_t)id.z * NC);
        uint4 q3 = *(const uint4*)(xb + (size_t)id.w * NC);
        uint32 a0[4] = {q0.x, q0.y, q0.z, q0.w};
        uint32 a1[4] = {q1.x, q1.y, q1.z, q1.w};
        uint32 a2[4] = {q2.x, q2.y, q2.z, q2.w};
        uint32 a3[4] = {q3.x, q3.y, q3.z, q3.w};
        uint32 pk[4];
        #pragma unroll
        for (int d = 0; d < 4; ++d) {
            float lo = cwv.x*bf_lo(a0[d]) + cwv.y*bf_lo(a1[d])
                     + cwv.z*bf_lo(a2[d]) + cwv.w*bf_lo(a3[d]);
            float hi = cwv.x*bf_hi(a0[d]) + cwv.y*bf_hi(a1[d])
                     + cwv.z*bf_hi(a2[d]) + cwv.w*bf_hi(a3[d]);
            pk[d] = f2bf(lo) | (f2bf(hi) << 16);
        }
        *(uint4*)(ldsB + pl * 144 + w * 16) = make_uint4(pk[0], pk[1], pk[2], pk[3]);
    }
    __syncthreads();

    // ---- main loop
    for (int kt = 0; kt < NKT2; ++kt) {
        int cur = kt & 1;
        uint4 q0, q1, q2, q3; float4 cwv;
        bool has_next = (kt + 1) < NKT2;
        if (has_next) {
            char* dstA = ldsA + (cur ^ 1) * 36864;
            #pragma unroll
            for (int j = 0; j < 5; ++j) {
                int chunk = j * 512 + t;
                if (chunk < 2304) {
                    int row  = chunk / 9;
                    int slot = chunk - row * 9; if (slot > 7) slot = 7;
                    gload16((const char*)wta + (size_t)row * ROWB
                                + (size_t)(kt + 1) * 128 + slot * 16,
                            dstA + chunk * 16);
                }
            }
            int kk = (kt + 1) >> 2;
            int c0 = ((kt + 1) & 3) * 64;
            int4 id = ci_l[kk * 64 + pl];
            cwv = cw_l[kk * 64 + pl];
            const ushort_t* xb = xtb + c0 + w * 8;
            q0 = *(const uint4*)(xb + (size_t)id.x * NC);
            q1 = *(const uint4*)(xb + (size_t)id.y * NC);
            q2 = *(const uint4*)(xb + (size_t)id.z * NC);
            q3 = *(const uint4*)(xb + (size_t)id.w * NC);
        }

        // compute: ds_read fragments + MFMA
        {
            const char* A  = ldsA + cur * 36864;
            const char* Bt = ldsB + cur * 9216;
            short8 av[2][4], bv[2][2];
            #pragma unroll
            for (int ks = 0; ks < 2; ++ks) {
                #pragma unroll
                for (int fo = 0; fo < 4; ++fo)
                    av[ks][fo] = *(const short8*)(A + (wo * 64 + fo * 16 + r16) * 144
                                                    + ks * 64 + g * 16);
                #pragma unroll
                for (int fp = 0; fp < 2; ++fp)
                    bv[ks][fp] = *(const short8*)(Bt + (wp * 32 + fp * 16 + r16) * 144
                                                     + ks * 64 + g * 16);
            }
            __builtin_amdgcn_s_setprio(1);
            #pragma unroll
            for (int ks = 0; ks < 2; ++ks)
                #pragma unroll
                for (int fo = 0; fo < 4; ++fo)
                    #pragma unroll
                    for (int fp = 0; fp < 2; ++fp)
                        acc[fo][fp] = __builtin_amdgcn_mfma_f32_16x16x32_bf16(
                            av[ks][fo], bv[ks][fp], acc[fo][fp], 0, 0, 0);
            __builtin_amdgcn_s_setprio(0);
        }

        if (has_next) {
            uint32 a0[4] = {q0.x, q0.y, q0.z, q0.w};
            uint32 a1[4] = {q1.x, q1.y, q1.z, q1.w};
            uint32 a2[4] = {q2.x, q2.y, q2.z, q2.w};
            uint32 a3[4] = {q3.x, q3.y, q3.z, q3.w};
            uint32 pk[4];
            #pragma unroll
            for (int d = 0; d < 4; ++d) {
                float lo = cwv.x*bf_lo(a0[d]) + cwv.y*bf_lo(a1[d])
                         + cwv.z*bf_lo(a2[d]) + cwv.w*bf_lo(a3[d]);
                float hi = cwv.x*bf_hi(a0[d]) + cwv.y*bf_hi(a1[d])
                         + cwv.z*bf_hi(a2[d]) + cwv.w*bf_hi(a3[d]);
                pk[d] = f2bf(lo) | (f2bf(hi) << 16);
            }
            *(uint4*)(ldsB + (cur ^ 1) * 9216 + pl * 144 + w * 16) =
                make_uint4(pk[0], pk[1], pk[2], pk[3]);
        }
        __syncthreads();
    }

    // ---- epilogue: C/D col(p)=lane&15+fp*16, row(o)=(lane>>4)*4+reg
    float* outb = out + ((size_t)b * NOC) * NP + (pt << 6);
    #pragma unroll
    for (int fo = 0; fo < 4; ++fo) {
        #pragma unroll
        for (int rr = 0; rr < 4; ++rr) {
            int o = wo * 64 + fo * 16 + g * 4 + rr;
            float bb = bias[o];
            #pragma unroll
            for (int fp = 0; fp < 2; ++fp)
                outb[(size_t)o * NP + wp * 32 + fp * 16 + r16] = acc[fo][fp][rr] + bb;
        }
    }
}

// ---------------------------------------------------------------- launch
extern "C" void kernel_launch(void* const* d_in, const int* in_sizes, int n_in,
                              void* d_out, int out_size, void* d_ws, size_t ws_size,
                              hipStream_t stream) {
    const float* x     = (const float*)d_in[0];
    const float* ow    = (const float*)d_in[1];
    const float* obias = (const float*)d_in[2];
    const float* wgt   = (const float*)d_in[3];
    const float* bias  = (const float*)d_in[4];
    float* out = (float*)d_out;

    char* ws = (char*)d_ws;
    float*    om   = (float*)ws;                     //  1,769,472 B
    ushort_t* owb  = (ushort_t*)(ws + 1769472);      //    147,456 B
    ushort_t* wta  = (ushort_t*)(ws + 1916928);      //  1,179,648 B
    ushort_t* xt   = (ushort_t*)(ws + 3096576);      //  8,388,608 B (tot ~11.5 MB)

    hipLaunchKernelGGL(wprep_A,    dim3(2304), dim3(256), 0, stream, wgt, wta);
    hipLaunchKernelGGL(owb_prep,   dim3(288),  dim3(256), 0, stream, ow, owb);
    hipLaunchKernelGGL(om_init,    dim3(1728), dim3(256), 0, stream, obias, om);
    hipLaunchKernelGGL(xprep2,     dim3(512),  dim3(256), 0, stream, x, xt);
    hipLaunchKernelGGL(offs_mfma2, dim3(512),  dim3(256), 0, stream, xt, owb, om);
    hipLaunchKernelGGL(dcn_main,   dim3(256),  dim3(512), 0, stream, wta, xt, om, bias, out);
}

// Round 12
// 157.643 us; speedup vs baseline: 1.0763x; 1.0763x over previous
//
#include <hip/hip_runtime.h>

// DCNv2 B=4,C=256,H=W=64,OC=256,K=9. Pipeline:
//   wprep_A   : weight -> WtA[o][ck] bf16 (ck=k*256+c)
//   owb_prep  : offset_w -> owb[k][32ch pad][256c] bf16
//   om_init   : om = obias broadcast
//   xprep2    : x NCHW f32 -> xT[b][p][c] bf16 (NHWC), LDS-transposed coalesced
//   offs_mfma3: offset conv as 9-shift MFMA GEMM, c-split x2, A-frags from
//               global (L2) directly -> no A LDS staging; atomic reduce -> om
//   gather3   : coords once per (k,p); 8c-per-lane uint4 gather -> S[b][p][ck]
//   gemm3     : bf16 MFMA 16x16x32, 128o x 64p tiles, BK=64 (36 barriers);
//               global_load_lds staging with WAVE-UNIFORM LDS dest +
//               per-lane pre-compensated SOURCE (rule #21 fix).

#define NB 4
#define NC 256
#define HW 64
#define NP 4096
#define NOC 256
#define NCK 2304
#define ROWB 4608           // bytes per ck-row (2304 * 2B)
#define NKT3 36             // 64-ck tiles

typedef __attribute__((ext_vector_type(8))) short short8;
typedef __attribute__((ext_vector_type(4))) float f32x4;
typedef unsigned short ushort_t;
typedef unsigned int uint32;

__device__ __forceinline__ void gload16(const void* g, void* l) {
    __builtin_amdgcn_global_load_lds(
        (const __attribute__((address_space(1))) unsigned int*)g,
        (__attribute__((address_space(3))) unsigned int*)l, 16, 0, 0);
}

__device__ __forceinline__ uint32 f2bf(float v) {
    uint32 b = __float_as_uint(v);
    return (b + 0x7FFFu + ((b >> 16) & 1u)) >> 16;   // RNE
}
__device__ __forceinline__ float bf_lo(uint32 u) { return __uint_as_float(u << 16); }
__device__ __forceinline__ float bf_hi(uint32 u) { return __uint_as_float(u & 0xFFFF0000u); }

// ---------------------------------------------------------------- wprep_A
__global__ __launch_bounds__(256) void wprep_A(const float* __restrict__ w,
                                               ushort_t* __restrict__ wta) {
    int e = blockIdx.x * 256 + threadIdx.x;     // < 256*2304
    int o  = e / NCK;
    int ck = e - o * NCK;
    int c = ck & 255;
    int k = ck >> 8;
    wta[e] = (ushort_t)f2bf(w[o * NCK + c * 9 + k]);
}

// ---------------------------------------------------------------- owb_prep
__global__ __launch_bounds__(256) void owb_prep(const float* __restrict__ ow,
                                                ushort_t* __restrict__ owb) {
    int e = blockIdx.x * 256 + threadIdx.x;     // < 73728
    int c = e & 255;
    int r = e >> 8;          // k*32 + ch
    int ch = r & 31;
    int k = r >> 5;
    float v = 0.f;
    if (ch < 27) v = ow[(ch * NC + c) * 9 + k];
    owb[e] = (ushort_t)f2bf(v);
}

// ---------------------------------------------------------------- om_init
__global__ __launch_bounds__(256) void om_init(const float* __restrict__ obias,
                                               float* __restrict__ om) {
    int g = blockIdx.x * 256 + threadIdx.x;     // < 4*27*4096
    int r = g >> 12;
    int ch = r % 27;
    om[g] = obias[ch];
}

// ---------------------------------------------------------------- xprep2
__global__ __launch_bounds__(256) void xprep2(const float* __restrict__ x,
                                              ushort_t* __restrict__ xt) {
    __shared__ float tr[128 * 65];    // 33280 B
    int bid = blockIdx.x;             // b*128 + cc*32 + pt
    int pt = bid & 31;
    int cc = (bid >> 5) & 3;
    int b  = bid >> 7;
    int t = threadIdx.x;
    int c0 = cc * 64;

    const float* xb = x + ((size_t)(b * NC + c0)) * NP + pt * 128;
    #pragma unroll
    for (int pass = 0; pass < 8; ++pass) {
        int c  = pass * 8 + (t >> 5);
        int p4 = (t & 31) * 4;
        float4 v = *(const float4*)(xb + (size_t)c * NP + p4);
        tr[(p4 + 0) * 65 + c] = v.x;
        tr[(p4 + 1) * 65 + c] = v.y;
        tr[(p4 + 2) * 65 + c] = v.z;
        tr[(p4 + 3) * 65 + c] = v.w;
    }
    __syncthreads();
    ushort_t* xto = xt + ((size_t)b * NP + pt * 128) * NC + c0;
    #pragma unroll
    for (int pass = 0; pass < 4; ++pass) {
        int e = pass * 256 + t;
        int p = e >> 3, seg = e & 7;
        const float* rp = &tr[p * 65 + seg * 8];
        uint32 pk[4];
        #pragma unroll
        for (int h = 0; h < 4; ++h)
            pk[h] = f2bf(rp[2 * h]) | (f2bf(rp[2 * h + 1]) << 16);
        *(uint4*)(xto + (size_t)p * NC + seg * 8) = make_uint4(pk[0], pk[1], pk[2], pk[3]);
    }
}

// ---------------------------------------------------------------- offs_mfma3
// om[b][27][y*64+p] += shift-GEMM over this block's half of c.
// Block=(b,y,h). LDS: only B-halo [198 rows][144B] (28512B) + f32 reduce (32KB).
// A-frags loaded straight from owb (147KB, L2-resident) into VGPRs.
__global__ __launch_bounds__(256) void offs_mfma3(const ushort_t* __restrict__ xt,
                                                  const ushort_t* __restrict__ owb,
                                                  float* __restrict__ om) {
    __shared__ __align__(16) char lds[32768];
    int bid = blockIdx.x;        // b*128 + y*2 + h
    int h = bid & 1;
    int y = (bid >> 1) & 63;
    int b = bid >> 7;
    int t = threadIdx.x;
    int lane = t & 63;
    int w = t >> 6;
    int r16 = lane & 15;
    int g   = lane >> 4;

    f32x4 acc[2][4];
    #pragma unroll
    for (int mf = 0; mf < 2; ++mf)
        #pragma unroll
        for (int nf = 0; nf < 4; ++nf) acc[mf][nf] = (f32x4){0.f, 0.f, 0.f, 0.f};

    const ushort_t* xtb = xt + ((size_t)b * NP) * NC;

    for (int ccc = 0; ccc < 2; ++ccc) {
        int c0 = (h * 2 + ccc) * 64;
        __syncthreads();
        // stage B halo tile: 198 rows (dy,xx) x 8 segs of 16B, zero OOB
        for (int e = t; e < 1584; e += 256) {
            int rr = e >> 3, seg = e & 7;
            int dy = (rr >= 132) ? 2 : (rr >= 66 ? 1 : 0);
            int xx = rr - dy * 66;
            int ys = y + dy - 1;
            int xs = xx - 1;
            uint4 v = make_uint4(0, 0, 0, 0);
            if (ys >= 0 && ys < 64 && xs >= 0 && xs < 64)
                v = *(const uint4*)(xtb + ((ys << 6) + xs) * NC + c0 + seg * 8);
            *(uint4*)(lds + rr * 144 + seg * 16) = v;
        }
        __syncthreads();

        // preload all A-frags for this chunk (up to 3 shifts x 2 mf x 2 ks)
        short8 af[3][2][2];
        #pragma unroll
        for (int jj = 0; jj < 3; ++jj) {
            int s = w + jj * 4;
            if (s < 9) {
                #pragma unroll
                for (int mf = 0; mf < 2; ++mf)
                    #pragma unroll
                    for (int ks = 0; ks < 2; ++ks)
                        af[jj][mf][ks] = *(const short8*)(owb
                            + (s * 32 + mf * 16 + r16) * 256 + c0 + ks * 32 + g * 8);
            }
        }
        #pragma unroll
        for (int jj = 0; jj < 3; ++jj) {
            int s = w + jj * 4;
            if (s < 9) {
                int dy = (s >= 6) ? 2 : (s >= 3 ? 1 : 0);
                int dx = s - dy * 3;
                #pragma unroll
                for (int ks = 0; ks < 2; ++ks) {
                    #pragma unroll
                    for (int nf = 0; nf < 4; ++nf) {
                        short8 bv = *(const short8*)(lds +
                            (dy * 66 + nf * 16 + r16 + dx) * 144 + ks * 64 + g * 16);
                        acc[0][nf] = __builtin_amdgcn_mfma_f32_16x16x32_bf16(
                            af[jj][0][ks], bv, acc[0][nf], 0, 0, 0);
                        acc[1][nf] = __builtin_amdgcn_mfma_f32_16x16x32_bf16(
                            af[jj][1][ks], bv, acc[1][nf], 0, 0, 0);
                    }
                }
            }
        }
    }
    __syncthreads();
    // cross-wave reduce: red[w][32 ch][64 p] f32
    float* red = (float*)lds;
    #pragma unroll
    for (int mf = 0; mf < 2; ++mf)
        #pragma unroll
        for (int nf = 0; nf < 4; ++nf)
            #pragma unroll
            for (int r = 0; r < 4; ++r) {
                int ch = mf * 16 + g * 4 + r;
                int p  = nf * 16 + r16;
                red[((w * 32 + ch) << 6) + p] = acc[mf][nf][r];
            }
    __syncthreads();
    for (int e = t; e < 27 * 64; e += 256) {
        int ch = e >> 6, p = e & 63;
        float sres = red[(ch << 6) + p] + red[((32 + ch) << 6) + p]
                   + red[((64 + ch) << 6) + p] + red[((96 + ch) << 6) + p];
        atomicAdd(&om[((size_t)(b * 27 + ch)) * NP + (y << 6) + p], sres);
    }
}

// ---------------------------------------------------------------- gather3
// Block=(b,k,y) with XCD affinity. Phase1: 64 threads compute row coords.
// Phase2: lane owns 8 c (uint4); half-waves process 2 p per iter, 8 iters.
__global__ __launch_bounds__(256) void gather3(const ushort_t* __restrict__ xt,
                                               const float* __restrict__ om,
                                               ushort_t* __restrict__ sb) {
    __shared__ __align__(16) int4   ci_l[64];
    __shared__ __align__(16) float4 cw_l[64];
    int g = blockIdx.x;                    // 2304 blocks
    int b = (g & 7) >> 1;                  // XCD pair per batch
    int r = ((g >> 3) << 1) | (g & 1);     // [0,576)
    int y = r & 63;
    int k = r >> 6;
    int t = threadIdx.x;

    if (t < 64) {
        int p = y * HW + t;
        const float* omb = om + ((size_t)b * 27) * NP;
        float o1 = omb[(size_t)k * NP + p];
        float o2 = omb[(size_t)(9 + k) * NP + p];
        float ml = omb[(size_t)(18 + k) * NP + p];
        float mask = 1.f / (1.f + expf(-ml));
        float sx = (float)t + (float)(k % 3) - 2.0f + o1;
        float sy = (float)y + (float)(k / 3) - 2.0f + o2;
        float x0f = floorf(sx), y0f = floorf(sy);
        float fx = sx - x0f, fy = sy - y0f;
        int idv[4]; float wgt[4];
        #pragma unroll
        for (int cy = 0; cy < 2; ++cy) {
            float yf = y0f + (float)cy;
            float wy = cy ? fy : 1.f - fy;
            #pragma unroll
            for (int cx = 0; cx < 2; ++cx) {
                float xf = x0f + (float)cx;
                float wx = cx ? fx : 1.f - fx;
                bool valid = (xf >= 0.f) && (xf <= 63.f) && (yf >= 0.f) && (yf <= 63.f);
                int xi = min(max((int)xf, 0), 63);
                int yi = min(max((int)yf, 0), 63);
                idv[cy * 2 + cx] = yi * HW + xi;
                wgt[cy * 2 + cx] = valid ? wx * wy * mask : 0.f;
            }
        }
        ci_l[t] = make_int4(idv[0], idv[1], idv[2], idv[3]);
        cw_l[t] = make_float4(wgt[0], wgt[1], wgt[2], wgt[3]);
    }
    __syncthreads();

    int lane = t & 63;
    int w = t >> 6;
    int half = lane >> 5;
    int co = (lane & 31) * 8;
    const ushort_t* xtb = xt + ((size_t)b * NP) * NC + co;
    ushort_t* sbb = sb + ((size_t)b * NP + (size_t)y * HW) * NCK + k * NC + co;

    #pragma unroll 1
    for (int i = 0; i < 8; ++i) {
        int pl = w * 16 + half * 8 + i;
        int4   id = ci_l[pl];
        float4 cw = cw_l[pl];
        uint4 q0 = *(const uint4*)(xtb + (size_t)id.x * NC);
        uint4 q1 = *(const uint4*)(xtb + (size_t)id.y * NC);
        uint4 q2 = *(const uint4*)(xtb + (size_t)id.z * NC);
        uint4 q3 = *(const uint4*)(xtb + (size_t)id.w * NC);
        uint32 a0[4] = {q0.x, q0.y, q0.z, q0.w};
        uint32 a1[4] = {q1.x, q1.y, q1.z, q1.w};
        uint32 a2[4] = {q2.x, q2.y, q2.z, q2.w};
        uint32 a3[4] = {q3.x, q3.y, q3.z, q3.w};
        uint32 pk[4];
        #pragma unroll
        for (int d = 0; d < 4; ++d) {
            float lo = cw.x*bf_lo(a0[d]) + cw.y*bf_lo(a1[d])
                     + cw.z*bf_lo(a2[d]) + cw.w*bf_lo(a3[d]);
            float hi = cw.x*bf_hi(a0[d]) + cw.y*bf_hi(a1[d])
                     + cw.z*bf_hi(a2[d]) + cw.w*bf_hi(a3[d]);
            pk[d] = f2bf(lo) | (f2bf(hi) << 16);
        }
        *(uint4*)(sbb + (size_t)pl * NCK) = make_uint4(pk[0], pk[1], pk[2], pk[3]);
    }
}

// ---------------------------------------------------------------- gemm3
// Block=(b,ot,pt): 128o x 64p tile, BK=64 -> 36 K-tiles. Grid 512 (2 blocks/CU).
// Staging (rule #21): LDS dest is WAVE-UNIFORM chunk base (HW adds lane*16);
// the per-lane SOURCE address is pre-compensated for the 144B-padded rows.
// 27 chunks of 1024B per buffer: 0..17 -> A (18432B), 18..26 -> B (9216B).
// Pad slots (col>=128) re-read real data (harmless). Per buf 27648B; dbuf 55296.
__global__ __launch_bounds__(256) void gemm3(const ushort_t* __restrict__ wta,
                                             const ushort_t* __restrict__ sb,
                                             const float* __restrict__ bias,
                                             float* __restrict__ out) {
    __shared__ __align__(16) char lds[2 * 27648];
    int bid = blockIdx.x;           // b*128 + ot*64 + pt
    int pt = bid & 63;
    int ot = (bid >> 6) & 1;
    int b  = bid >> 7;
    int t = threadIdx.x;
    int lane = t & 63;
    int w = t >> 6;
    int wo = w & 1;
    int wp = w >> 1;
    int r16 = lane & 15;
    int g   = lane >> 4;

    const char* Abase = (const char*)wta + (size_t)(ot * 128) * ROWB;
    const char* Bbase = (const char*)sb + (size_t)b * NP * ROWB
                                        + (size_t)(pt * 64) * ROWB;
    const char* srcp[7]; int dstp[7]; bool jv[7];
    #pragma unroll
    for (int jj = 0; jj < 7; ++jj) {
        int j = w + jj * 4;
        jv[jj] = (j < 27);
        if (j < 18) {
            int d = j * 1024 + lane * 16;       // byte in A LDS region
            int row = d / 144, col = d - row * 144;
            if (col >= 128) col = 112;          // pad slot: harmless re-read
            srcp[jj] = Abase + (size_t)row * ROWB + col;
            dstp[jj] = j * 1024;                // wave-uniform
        } else if (j < 27) {
            int j2 = j - 18;
            int d = j2 * 1024 + lane * 16;      // byte in B LDS region
            int row = d / 144, col = d - row * 144;
            if (col >= 128) col = 112;
            srcp[jj] = Bbase + (size_t)row * ROWB + col;
            dstp[jj] = 18432 + j2 * 1024;       // wave-uniform
        } else { srcp[jj] = Abase; dstp[jj] = 0; }
    }

    f32x4 acc[4][2];
    #pragma unroll
    for (int fo = 0; fo < 4; ++fo)
        #pragma unroll
        for (int fp = 0; fp < 2; ++fp) acc[fo][fp] = (f32x4){0.f, 0.f, 0.f, 0.f};

    // prologue: stage kt=0 into buf 0
    #pragma unroll
    for (int jj = 0; jj < 7; ++jj)
        if (jv[jj]) gload16(srcp[jj], lds + dstp[jj]);
    __syncthreads();

    for (int kt = 0; kt < NKT3; ++kt) {
        int q = kt & 1;
        if (kt + 1 < NKT3) {
            char* dst = lds + (q ^ 1) * 27648;
            size_t ko = (size_t)(kt + 1) * 128;   // 64 ck * 2B per tile
            #pragma unroll
            for (int jj = 0; jj < 7; ++jj)
                if (jv[jj]) gload16(srcp[jj] + ko, dst + dstp[jj]);
        }
        const char* buf = lds + q * 27648;
        short8 av[2][4], bv[2][2];
        #pragma unroll
        for (int ks = 0; ks < 2; ++ks) {
            #pragma unroll
            for (int fo = 0; fo < 4; ++fo)
                av[ks][fo] = *(const short8*)(buf + (wo * 64 + fo * 16 + r16) * 144
                                                 + ks * 64 + g * 16);
            #pragma unroll
            for (int fp = 0; fp < 2; ++fp)
                bv[ks][fp] = *(const short8*)(buf + 18432
                                                 + (wp * 32 + fp * 16 + r16) * 144
                                                 + ks * 64 + g * 16);
        }
        #pragma unroll
        for (int ks = 0; ks < 2; ++ks)
            #pragma unroll
            for (int fo = 0; fo < 4; ++fo)
                #pragma unroll
                for (int fp = 0; fp < 2; ++fp)
                    acc[fo][fp] = __builtin_amdgcn_mfma_f32_16x16x32_bf16(
                        av[ks][fo], bv[ks][fp], acc[fo][fp], 0, 0, 0);
        __syncthreads();
    }

    // C/D: col(p)=lane&15, row(o)=(lane>>4)*4+reg
    int obase = ot * 128 + wo * 64;
    int pbase = pt * 64 + wp * 32 + r16;
    float* outb = out + ((size_t)b * NOC) * NP;
    #pragma unroll
    for (int fo = 0; fo < 4; ++fo) {
        #pragma unroll
        for (int rr = 0; rr < 4; ++rr) {
            int o = obase + fo * 16 + g * 4 + rr;
            float bb = bias[o];
            #pragma unroll
            for (int fp = 0; fp < 2; ++fp)
                outb[(size_t)o * NP + pbase + fp * 16] = acc[fo][fp][rr] + bb;
        }
    }
}

// ---------------------------------------------------------------- launch
extern "C" void kernel_launch(void* const* d_in, const int* in_sizes, int n_in,
                              void* d_out, int out_size, void* d_ws, size_t ws_size,
                              hipStream_t stream) {
    const float* x     = (const float*)d_in[0];
    const float* ow    = (const float*)d_in[1];
    const float* obias = (const float*)d_in[2];
    const float* wgt   = (const float*)d_in[3];
    const float* bias  = (const float*)d_in[4];
    float* out = (float*)d_out;

    char* ws = (char*)d_ws;
    float*    om   = (float*)ws;                     //  1,769,472 B
    ushort_t* owb  = (ushort_t*)(ws + 1769472);      //    147,456 B
    ushort_t* wta  = (ushort_t*)(ws + 1916928);      //  1,179,648 B
    ushort_t* xt   = (ushort_t*)(ws + 3096576);      //  8,388,608 B
    ushort_t* sbuf = (ushort_t*)(ws + 11485184);     // 75,497,472 B (tot ~87 MB)

    hipLaunchKernelGGL(wprep_A,    dim3(2304), dim3(256), 0, stream, wgt, wta);
    hipLaunchKernelGGL(owb_prep,   dim3(288),  dim3(256), 0, stream, ow, owb);
    hipLaunchKernelGGL(om_init,    dim3(1728), dim3(256), 0, stream, obias, om);
    hipLaunchKernelGGL(xprep2,     dim3(512),  dim3(256), 0, stream, x, xt);
    hipLaunchKernelGGL(offs_mfma3, dim3(512),  dim3(256), 0, stream, xt, owb, om);
    hipLaunchKernelGGL(gather3,    dim3(2304), dim3(256), 0, stream, xt, om, sbuf);
    hipLaunchKernelGGL(gemm3,      dim3(512),  dim3(256), 0, stream, wta, sbuf, bias, out);
}

// Round 13
// 146.411 us; speedup vs baseline: 1.1588x; 1.0767x over previous
//
#include <hip/hip_runtime.h>

// DCNv2 B=4,C=256,H=W=64,OC=256,K=9. Pipeline:
//   wprep_A   : weight -> WtA[o][ck] bf16 (ck=k*256+c)
//   owb_prep  : offset_w -> owb[k][32ch pad][256c] bf16
//   om_init   : om = obias broadcast
//   xprep2    : x NCHW f32 -> xT[b][p][c] bf16 (NHWC), LDS-transposed coalesced
//   offs_mfma3: offset conv as 9-shift MFMA GEMM, c-split x2, A-frags from
//               global (L2) directly -> no A LDS staging; atomic reduce -> om
//   gather4   : coords once per (k,p); 8c-per-lane uint4 gather, 4-way unrolled
//               batched loads (16 in flight) -> S[b][p][ck]
//   gemm3     : bf16 MFMA 16x16x32, 128o x 64p tiles, BK=64; rule-#21-correct
//               global_load_lds staging (wave-uniform dest, remapped source).

#define NB 4
#define NC 256
#define HW 64
#define NP 4096
#define NOC 256
#define NCK 2304
#define ROWB 4608           // bytes per ck-row (2304 * 2B)
#define NKT3 36             // 64-ck tiles

typedef __attribute__((ext_vector_type(8))) short short8;
typedef __attribute__((ext_vector_type(4))) float f32x4;
typedef unsigned short ushort_t;
typedef unsigned int uint32;

__device__ __forceinline__ void gload16(const void* g, void* l) {
    __builtin_amdgcn_global_load_lds(
        (const __attribute__((address_space(1))) unsigned int*)g,
        (__attribute__((address_space(3))) unsigned int*)l, 16, 0, 0);
}

__device__ __forceinline__ uint32 f2bf(float v) {
    uint32 b = __float_as_uint(v);
    return (b + 0x7FFFu + ((b >> 16) & 1u)) >> 16;   // RNE
}
__device__ __forceinline__ float bf_lo(uint32 u) { return __uint_as_float(u << 16); }
__device__ __forceinline__ float bf_hi(uint32 u) { return __uint_as_float(u & 0xFFFF0000u); }

// ---------------------------------------------------------------- wprep_A
__global__ __launch_bounds__(256) void wprep_A(const float* __restrict__ w,
                                               ushort_t* __restrict__ wta) {
    int e = blockIdx.x * 256 + threadIdx.x;     // < 256*2304
    int o  = e / NCK;
    int ck = e - o * NCK;
    int c = ck & 255;
    int k = ck >> 8;
    wta[e] = (ushort_t)f2bf(w[o * NCK + c * 9 + k]);
}

// ---------------------------------------------------------------- owb_prep
__global__ __launch_bounds__(256) void owb_prep(const float* __restrict__ ow,
                                                ushort_t* __restrict__ owb) {
    int e = blockIdx.x * 256 + threadIdx.x;     // < 73728
    int c = e & 255;
    int r = e >> 8;          // k*32 + ch
    int ch = r & 31;
    int k = r >> 5;
    float v = 0.f;
    if (ch < 27) v = ow[(ch * NC + c) * 9 + k];
    owb[e] = (ushort_t)f2bf(v);
}

// ---------------------------------------------------------------- om_init
__global__ __launch_bounds__(256) void om_init(const float* __restrict__ obias,
                                               float* __restrict__ om) {
    int g = blockIdx.x * 256 + threadIdx.x;     // < 4*27*4096
    int r = g >> 12;
    int ch = r % 27;
    om[g] = obias[ch];
}

// ---------------------------------------------------------------- xprep2
__global__ __launch_bounds__(256) void xprep2(const float* __restrict__ x,
                                              ushort_t* __restrict__ xt) {
    __shared__ float tr[128 * 65];    // 33280 B
    int bid = blockIdx.x;             // b*128 + cc*32 + pt
    int pt = bid & 31;
    int cc = (bid >> 5) & 3;
    int b  = bid >> 7;
    int t = threadIdx.x;
    int c0 = cc * 64;

    const float* xb = x + ((size_t)(b * NC + c0)) * NP + pt * 128;
    #pragma unroll
    for (int pass = 0; pass < 8; ++pass) {
        int c  = pass * 8 + (t >> 5);
        int p4 = (t & 31) * 4;
        float4 v = *(const float4*)(xb + (size_t)c * NP + p4);
        tr[(p4 + 0) * 65 + c] = v.x;
        tr[(p4 + 1) * 65 + c] = v.y;
        tr[(p4 + 2) * 65 + c] = v.z;
        tr[(p4 + 3) * 65 + c] = v.w;
    }
    __syncthreads();
    ushort_t* xto = xt + ((size_t)b * NP + pt * 128) * NC + c0;
    #pragma unroll
    for (int pass = 0; pass < 4; ++pass) {
        int e = pass * 256 + t;
        int p = e >> 3, seg = e & 7;
        const float* rp = &tr[p * 65 + seg * 8];
        uint32 pk[4];
        #pragma unroll
        for (int h = 0; h < 4; ++h)
            pk[h] = f2bf(rp[2 * h]) | (f2bf(rp[2 * h + 1]) << 16);
        *(uint4*)(xto + (size_t)p * NC + seg * 8) = make_uint4(pk[0], pk[1], pk[2], pk[3]);
    }
}

// ---------------------------------------------------------------- offs_mfma3
__global__ __launch_bounds__(256) void offs_mfma3(const ushort_t* __restrict__ xt,
                                                  const ushort_t* __restrict__ owb,
                                                  float* __restrict__ om) {
    __shared__ __align__(16) char lds[32768];
    int bid = blockIdx.x;        // b*128 + y*2 + h
    int h = bid & 1;
    int y = (bid >> 1) & 63;
    int b = bid >> 7;
    int t = threadIdx.x;
    int lane = t & 63;
    int w = t >> 6;
    int r16 = lane & 15;
    int g   = lane >> 4;

    f32x4 acc[2][4];
    #pragma unroll
    for (int mf = 0; mf < 2; ++mf)
        #pragma unroll
        for (int nf = 0; nf < 4; ++nf) acc[mf][nf] = (f32x4){0.f, 0.f, 0.f, 0.f};

    const ushort_t* xtb = xt + ((size_t)b * NP) * NC;

    for (int ccc = 0; ccc < 2; ++ccc) {
        int c0 = (h * 2 + ccc) * 64;
        __syncthreads();
        // stage B halo tile: 198 rows (dy,xx) x 8 segs of 16B, zero OOB
        for (int e = t; e < 1584; e += 256) {
            int rr = e >> 3, seg = e & 7;
            int dy = (rr >= 132) ? 2 : (rr >= 66 ? 1 : 0);
            int xx = rr - dy * 66;
            int ys = y + dy - 1;
            int xs = xx - 1;
            uint4 v = make_uint4(0, 0, 0, 0);
            if (ys >= 0 && ys < 64 && xs >= 0 && xs < 64)
                v = *(const uint4*)(xtb + ((ys << 6) + xs) * NC + c0 + seg * 8);
            *(uint4*)(lds + rr * 144 + seg * 16) = v;
        }
        __syncthreads();

        // preload all A-frags for this chunk (up to 3 shifts x 2 mf x 2 ks)
        short8 af[3][2][2];
        #pragma unroll
        for (int jj = 0; jj < 3; ++jj) {
            int s = w + jj * 4;
            if (s < 9) {
                #pragma unroll
                for (int mf = 0; mf < 2; ++mf)
                    #pragma unroll
                    for (int ks = 0; ks < 2; ++ks)
                        af[jj][mf][ks] = *(const short8*)(owb
                            + (s * 32 + mf * 16 + r16) * 256 + c0 + ks * 32 + g * 8);
            }
        }
        #pragma unroll
        for (int jj = 0; jj < 3; ++jj) {
            int s = w + jj * 4;
            if (s < 9) {
                int dy = (s >= 6) ? 2 : (s >= 3 ? 1 : 0);
                int dx = s - dy * 3;
                #pragma unroll
                for (int ks = 0; ks < 2; ++ks) {
                    #pragma unroll
                    for (int nf = 0; nf < 4; ++nf) {
                        short8 bv = *(const short8*)(lds +
                            (dy * 66 + nf * 16 + r16 + dx) * 144 + ks * 64 + g * 16);
                        acc[0][nf] = __builtin_amdgcn_mfma_f32_16x16x32_bf16(
                            af[jj][0][ks], bv, acc[0][nf], 0, 0, 0);
                        acc[1][nf] = __builtin_amdgcn_mfma_f32_16x16x32_bf16(
                            af[jj][1][ks], bv, acc[1][nf], 0, 0, 0);
                    }
                }
            }
        }
    }
    __syncthreads();
    // cross-wave reduce: red[w][32 ch][64 p] f32
    float* red = (float*)lds;
    #pragma unroll
    for (int mf = 0; mf < 2; ++mf)
        #pragma unroll
        for (int nf = 0; nf < 4; ++nf)
            #pragma unroll
            for (int r = 0; r < 4; ++r) {
                int ch = mf * 16 + g * 4 + r;
                int p  = nf * 16 + r16;
                red[((w * 32 + ch) << 6) + p] = acc[mf][nf][r];
            }
    __syncthreads();
    for (int e = t; e < 27 * 64; e += 256) {
        int ch = e >> 6, p = e & 63;
        float sres = red[(ch << 6) + p] + red[((32 + ch) << 6) + p]
                   + red[((64 + ch) << 6) + p] + red[((96 + ch) << 6) + p];
        atomicAdd(&om[((size_t)(b * 27 + ch)) * NP + (y << 6) + p], sres);
    }
}

// ---------------------------------------------------------------- gather4
// Block=(b,k,y) with XCD affinity. Phase1: 64 threads compute row coords.
// Phase2: lane owns 8 c (uint4); 2 chunks x 4-way unroll: 16 corner loads
// issued back-to-back (MLP) before the FMA/pack/store of the chunk.
__global__ __launch_bounds__(256) void gather4(const ushort_t* __restrict__ xt,
                                               const float* __restrict__ om,
                                               ushort_t* __restrict__ sb) {
    __shared__ __align__(16) int4   ci_l[64];
    __shared__ __align__(16) float4 cw_l[64];
    int g = blockIdx.x;                    // 2304 blocks
    int b = (g & 7) >> 1;                  // XCD pair per batch
    int r = ((g >> 3) << 1) | (g & 1);     // [0,576)
    int y = r & 63;
    int k = r >> 6;
    int t = threadIdx.x;

    if (t < 64) {
        int p = y * HW + t;
        const float* omb = om + ((size_t)b * 27) * NP;
        float o1 = omb[(size_t)k * NP + p];
        float o2 = omb[(size_t)(9 + k) * NP + p];
        float ml = omb[(size_t)(18 + k) * NP + p];
        float mask = 1.f / (1.f + expf(-ml));
        float sx = (float)t + (float)(k % 3) - 2.0f + o1;
        float sy = (float)y + (float)(k / 3) - 2.0f + o2;
        float x0f = floorf(sx), y0f = floorf(sy);
        float fx = sx - x0f, fy = sy - y0f;
        int idv[4]; float wgt[4];
        #pragma unroll
        for (int cy = 0; cy < 2; ++cy) {
            float yf = y0f + (float)cy;
            float wy = cy ? fy : 1.f - fy;
            #pragma unroll
            for (int cx = 0; cx < 2; ++cx) {
                float xf = x0f + (float)cx;
                float wx = cx ? fx : 1.f - fx;
                bool valid = (xf >= 0.f) && (xf <= 63.f) && (yf >= 0.f) && (yf <= 63.f);
                int xi = min(max((int)xf, 0), 63);
                int yi = min(max((int)yf, 0), 63);
                idv[cy * 2 + cx] = yi * HW + xi;
                wgt[cy * 2 + cx] = valid ? wx * wy * mask : 0.f;
            }
        }
        ci_l[t] = make_int4(idv[0], idv[1], idv[2], idv[3]);
        cw_l[t] = make_float4(wgt[0], wgt[1], wgt[2], wgt[3]);
    }
    __syncthreads();

    int lane = t & 63;
    int w = t >> 6;
    int half = lane >> 5;
    int co = (lane & 31) * 8;
    const ushort_t* xtb = xt + ((size_t)b * NP) * NC + co;
    ushort_t* sbb = sb + ((size_t)b * NP + (size_t)y * HW) * NCK + k * NC + co;

    #pragma unroll 1
    for (int ii = 0; ii < 2; ++ii) {
        int pl0 = w * 16 + half * 8 + ii * 4;
        int4   id4[4]; float4 cw4[4];
        #pragma unroll
        for (int j = 0; j < 4; ++j) {
            id4[j] = ci_l[pl0 + j];
            cw4[j] = cw_l[pl0 + j];
        }
        uint4 q[4][4];
        #pragma unroll
        for (int j = 0; j < 4; ++j) {
            q[j][0] = *(const uint4*)(xtb + (size_t)id4[j].x * NC);
            q[j][1] = *(const uint4*)(xtb + (size_t)id4[j].y * NC);
            q[j][2] = *(const uint4*)(xtb + (size_t)id4[j].z * NC);
            q[j][3] = *(const uint4*)(xtb + (size_t)id4[j].w * NC);
        }
        #pragma unroll
        for (int j = 0; j < 4; ++j) {
            uint32 a0[4] = {q[j][0].x, q[j][0].y, q[j][0].z, q[j][0].w};
            uint32 a1[4] = {q[j][1].x, q[j][1].y, q[j][1].z, q[j][1].w};
            uint32 a2[4] = {q[j][2].x, q[j][2].y, q[j][2].z, q[j][2].w};
            uint32 a3[4] = {q[j][3].x, q[j][3].y, q[j][3].z, q[j][3].w};
            float4 cw = cw4[j];
            uint32 pk[4];
            #pragma unroll
            for (int d = 0; d < 4; ++d) {
                float lo = cw.x*bf_lo(a0[d]) + cw.y*bf_lo(a1[d])
                         + cw.z*bf_lo(a2[d]) + cw.w*bf_lo(a3[d]);
                float hi = cw.x*bf_hi(a0[d]) + cw.y*bf_hi(a1[d])
                         + cw.z*bf_hi(a2[d]) + cw.w*bf_hi(a3[d]);
                pk[d] = f2bf(lo) | (f2bf(hi) << 16);
            }
            *(uint4*)(sbb + (size_t)(pl0 + j) * NCK) =
                make_uint4(pk[0], pk[1], pk[2], pk[3]);
        }
    }
}

// ---------------------------------------------------------------- gemm3
// Block=(b,ot,pt): 128o x 64p tile, BK=64 -> 36 K-tiles. Grid 512 (2 blocks/CU).
// Staging (rule #21): LDS dest is WAVE-UNIFORM chunk base (HW adds lane*16);
// the per-lane SOURCE address is pre-compensated for the 144B-padded rows.
// 27 chunks of 1024B per buffer: 0..17 -> A (18432B), 18..26 -> B (9216B).
__global__ __launch_bounds__(256) void gemm3(const ushort_t* __restrict__ wta,
                                             const ushort_t* __restrict__ sb,
                                             const float* __restrict__ bias,
                                             float* __restrict__ out) {
    __shared__ __align__(16) char lds[2 * 27648];
    int bid = blockIdx.x;           // b*128 + ot*64 + pt
    int pt = bid & 63;
    int ot = (bid >> 6) & 1;
    int b  = bid >> 7;
    int t = threadIdx.x;
    int lane = t & 63;
    int w = t >> 6;
    int wo = w & 1;
    int wp = w >> 1;
    int r16 = lane & 15;
    int g   = lane >> 4;

    const char* Abase = (const char*)wta + (size_t)(ot * 128) * ROWB;
    const char* Bbase = (const char*)sb + (size_t)b * NP * ROWB
                                        + (size_t)(pt * 64) * ROWB;
    const char* srcp[7]; int dstp[7]; bool jv[7];
    #pragma unroll
    for (int jj = 0; jj < 7; ++jj) {
        int j = w + jj * 4;
        jv[jj] = (j < 27);
        if (j < 18) {
            int d = j * 1024 + lane * 16;       // byte in A LDS region
            int row = d / 144, col = d - row * 144;
            if (col >= 128) col = 112;          // pad slot: harmless re-read
            srcp[jj] = Abase + (size_t)row * ROWB + col;
            dstp[jj] = j * 1024;                // wave-uniform
        } else if (j < 27) {
            int j2 = j - 18;
            int d = j2 * 1024 + lane * 16;      // byte in B LDS region
            int row = d / 144, col = d - row * 144;
            if (col >= 128) col = 112;
            srcp[jj] = Bbase + (size_t)row * ROWB + col;
            dstp[jj] = 18432 + j2 * 1024;       // wave-uniform
        } else { srcp[jj] = Abase; dstp[jj] = 0; }
    }

    f32x4 acc[4][2];
    #pragma unroll
    for (int fo = 0; fo < 4; ++fo)
        #pragma unroll
        for (int fp = 0; fp < 2; ++fp) acc[fo][fp] = (f32x4){0.f, 0.f, 0.f, 0.f};

    // prologue: stage kt=0 into buf 0
    #pragma unroll
    for (int jj = 0; jj < 7; ++jj)
        if (jv[jj]) gload16(srcp[jj], lds + dstp[jj]);
    __syncthreads();

    for (int kt = 0; kt < NKT3; ++kt) {
        int q = kt & 1;
        if (kt + 1 < NKT3) {
            char* dst = lds + (q ^ 1) * 27648;
            size_t ko = (size_t)(kt + 1) * 128;   // 64 ck * 2B per tile
            #pragma unroll
            for (int jj = 0; jj < 7; ++jj)
                if (jv[jj]) gload16(srcp[jj] + ko, dst + dstp[jj]);
        }
        const char* buf = lds + q * 27648;
        short8 av[2][4], bv[2][2];
        #pragma unroll
        for (int ks = 0; ks < 2; ++ks) {
            #pragma unroll
            for (int fo = 0; fo < 4; ++fo)
                av[ks][fo] = *(const short8*)(buf + (wo * 64 + fo * 16 + r16) * 144
                                                 + ks * 64 + g * 16);
            #pragma unroll
            for (int fp = 0; fp < 2; ++fp)
                bv[ks][fp] = *(const short8*)(buf + 18432
                                                 + (wp * 32 + fp * 16 + r16) * 144
                                                 + ks * 64 + g * 16);
        }
        #pragma unroll
        for (int ks = 0; ks < 2; ++ks)
            #pragma unroll
            for (int fo = 0; fo < 4; ++fo)
                #pragma unroll
                for (int fp = 0; fp < 2; ++fp)
                    acc[fo][fp] = __builtin_amdgcn_mfma_f32_16x16x32_bf16(
                        av[ks][fo], bv[ks][fp], acc[fo][fp], 0, 0, 0);
        __syncthreads();
    }

    // C/D: col(p)=lane&15, row(o)=(lane>>4)*4+reg
    int obase = ot * 128 + wo * 64;
    int pbase = pt * 64 + wp * 32 + r16;
    float* outb = out + ((size_t)b * NOC) * NP;
    #pragma unroll
    for (int fo = 0; fo < 4; ++fo) {
        #pragma unroll
        for (int rr = 0; rr < 4; ++rr) {
            int o = obase + fo * 16 + g * 4 + rr;
            float bb = bias[o];
            #pragma unroll
            for (int fp = 0; fp < 2; ++fp)
                outb[(size_t)o * NP + pbase + fp * 16] = acc[fo][fp][rr] + bb;
        }
    }
}

// ---------------------------------------------------------------- launch
extern "C" void kernel_launch(void* const* d_in, const int* in_sizes, int n_in,
                              void* d_out, int out_size, void* d_ws, size_t ws_size,
                              hipStream_t stream) {
    const float* x     = (const float*)d_in[0];
    const float* ow    = (const float*)d_in[1];
    const float* obias = (const float*)d_in[2];
    const float* wgt   = (const float*)d_in[3];
    const float* bias  = (const float*)d_in[4];
    float* out = (float*)d_out;

    char* ws = (char*)d_ws;
    float*    om   = (float*)ws;                     //  1,769,472 B
    ushort_t* owb  = (ushort_t*)(ws + 1769472);      //    147,456 B
    ushort_t* wta  = (ushort_t*)(ws + 1916928);      //  1,179,648 B
    ushort_t* xt   = (ushort_t*)(ws + 3096576);      //  8,388,608 B
    ushort_t* sbuf = (ushort_t*)(ws + 11485184);     // 75,497,472 B (tot ~87 MB)

    hipLaunchKernelGGL(wprep_A,    dim3(2304), dim3(256), 0, stream, wgt, wta);
    hipLaunchKernelGGL(owb_prep,   dim3(288),  dim3(256), 0, stream, ow, owb);
    hipLaunchKernelGGL(om_init,    dim3(1728), dim3(256), 0, stream, obias, om);
    hipLaunchKernelGGL(xprep2,     dim3(512),  dim3(256), 0, stream, x, xt);
    hipLaunchKernelGGL(offs_mfma3, dim3(512),  dim3(256), 0, stream, xt, owb, om);
    hipLaunchKernelGGL(gather4,    dim3(2304), dim3(256), 0, stream, xt, om, sbuf);
    hipLaunchKernelGGL(gemm3,      dim3(512),  dim3(256), 0, stream, wta, sbuf, bias, out);
}